// Round 1
// baseline (3008.341 us; speedup 1.0000x reference)
//
#include <hip/hip_runtime.h>
#include <hip/hip_bf16.h>

#define BB 2048
#define TT 128
#define NN (BB*TT)          // 262144
#define NVAL NN

// workspace layout (float offsets)
#define OFF_WCA   0u          // 96x8 combined air input weights
#define OFF_BCA   768u        // 96
#define OFF_WCM   864u        // 96x8 combined m input weights
#define OFF_BCM   1632u       // 96
#define OFF_W0T   2048u       // 64x256  W0 transposed
#define OFF_W1T   18432u      // 256x256 W1 transposed
#define OFF_AIRF  83968u      // B*T*32 air_feat
#define OFF_MF    8472576u    // 2B*T*32 m_feat
#define OFF_MASK  25249792u   // N*2 mask floats
#define OFF_ATTN  25774080u   // N*32 attn output

// ---------------- prep: combined input weights + transposed MLP weights ----
__global__ __launch_bounds__(256) void prep_kernel(
    const float* __restrict__ enc_air_W, const float* __restrict__ enc_air_b,
    const float* __restrict__ enc_m_W,   const float* __restrict__ enc_m_b,
    const float* __restrict__ air_Wih,   const float* __restrict__ air_bih,
    const float* __restrict__ m_Wih,     const float* __restrict__ m_bih,
    const float* __restrict__ W0,        const float* __restrict__ W1,
    float* __restrict__ ws)
{
    int b = blockIdx.x, t = threadIdx.x;
    if (b < 256) {
        // W1T[k=b][o=t] = W1[o][k]
        ws[OFF_W1T + b*256 + t] = W1[t*256 + b];
    } else if (b == 256) {
        for (int idx = t; idx < 64*256; idx += 256) {
            int k = idx >> 8, o = idx & 255;
            ws[OFF_W0T + k*256 + o] = W0[o*64 + k];
        }
    } else { // b == 257
        if (t < 96) {
            float bacc = air_bih[t];
            for (int i = 0; i < 7; i++) {
                float s = 0.f;
                for (int k = 0; k < 32; k++) s += air_Wih[t*32+k] * enc_air_W[k*7+i];
                ws[OFF_WCA + t*8 + i] = s;
            }
            for (int k = 0; k < 32; k++) bacc += air_Wih[t*32+k] * enc_air_b[k];
            ws[OFF_BCA + t] = bacc;

            float bacc2 = m_bih[t];
            for (int i = 0; i < 4; i++) {
                float s = 0.f;
                for (int k = 0; k < 32; k++) s += m_Wih[t*32+k] * enc_m_W[k*4+i];
                ws[OFF_WCM + t*8 + i] = s;
            }
            for (int k = 0; k < 32; k++) bacc2 += m_Wih[t*32+k] * enc_m_b[k];
            ws[OFF_BCM + t] = bacc2;
        }
    }
}

// ---------------- GRU ------------------------------------------------------
template<int NI, bool DO_MASK>
__device__ void gru_row(const float* __restrict__ in_base,      // pre-offset obs row
                        const float* __restrict__ Wc,           // 96x8
                        const float* __restrict__ bc,           // 96
                        const float* __restrict__ Whh,          // 96x32
                        const float* __restrict__ bhh,          // 96
                        float h0,
                        float* __restrict__ feat_out,           // row base (T,32)
                        float* __restrict__ hT_out,
                        float* __restrict__ mask_out,           // base + t*2
                        int lane)
{
    float wr[32], wz[32], wn[32];
    #pragma unroll
    for (int k = 0; k < 32; k++) {
        wr[k] = Whh[lane*32 + k];
        wz[k] = Whh[(32+lane)*32 + k];
        wn[k] = Whh[(64+lane)*32 + k];
    }
    float cr[NI], cz[NI], cn[NI];
    #pragma unroll
    for (int i = 0; i < NI; i++) {
        cr[i] = Wc[lane*8 + i];
        cz[i] = Wc[(32+lane)*8 + i];
        cn[i] = Wc[(64+lane)*8 + i];
    }
    const float bcr = bc[lane], bcz = bc[32+lane], bcn = bc[64+lane];
    const float bhr = bhh[lane], bhz = bhh[32+lane], bhn = bhh[64+lane];

    float h = h0;
    for (int t = 0; t < TT; t++) {
        float xin = (lane < NI) ? in_base[t*15 + lane] : 0.f;
        float ar = bcr, az = bcz, an = bcn;
        bool ok = true;
        #pragma unroll
        for (int i = 0; i < NI; i++) {
            float v = __shfl(xin, i, 32);
            ar += cr[i]*v; az += cz[i]*v; an += cn[i]*v;
            if (DO_MASK) {
                const float c   = ((i & 1) == 0) ? 1.f : 0.f;
                const float thr = ((i & 1) == 0) ? 1.00001e-5f : 1e-8f;
                ok = ok & (fabsf(v - c) <= thr);
            }
        }
        float hr = bhr, hz = bhz, hn = bhn;
        #pragma unroll
        for (int k = 0; k < 32; k++) {
            float hv = __shfl(h, k, 32);
            hr += wr[k]*hv; hz += wz[k]*hv; hn += wn[k]*hv;
        }
        float r = 1.f / (1.f + __expf(-(ar + hr)));
        float z = 1.f / (1.f + __expf(-(az + hz)));
        float pre = an + r*hn;
        float e2 = __expf(2.f*pre);
        float n = 1.f - 2.f/(e2 + 1.f);
        h = n + z*(h - n);
        feat_out[t*32 + lane] = h;
        if (DO_MASK) {
            if (lane == 0) mask_out[t*2] = ok ? 1.f : 0.f;
        }
    }
    *hT_out = h;
}

__global__ __launch_bounds__(256) void gru_kernel(
    const float* __restrict__ obs, const float* __restrict__ rnn,
    const float* __restrict__ ws_c,
    const float* __restrict__ air_Whh, const float* __restrict__ air_bhh,
    const float* __restrict__ m_Whh,   const float* __restrict__ m_bhh,
    float* __restrict__ air_feat, float* __restrict__ m_feat,
    float* __restrict__ mask_f, float* __restrict__ nh_out)
{
    int lane = threadIdx.x & 31;
    int r = blockIdx.x*8 + (threadIdx.x >> 5);
    if (r < BB) {
        const float* in_base = obs + r*(TT*15) + 8;
        float h0 = rnn[r*96 + lane];
        gru_row<7,false>(in_base, ws_c + OFF_WCA, ws_c + OFF_BCA,
                         air_Whh, air_bhh, h0,
                         air_feat + (size_t)r*TT*32,
                         nh_out + r*96 + lane, nullptr, lane);
    } else {
        int i = r - BB;
        int b = (i < BB) ? i : i - BB;
        int slot = (i < BB) ? 0 : 1;
        const float* in_base = obs + b*(TT*15) + slot*4;
        float h0 = rnn[(i >> 1)*96 + 32 + (i & 1)*32 + lane];
        gru_row<4,true>(in_base, ws_c + OFF_WCM, ws_c + OFF_BCM,
                        m_Whh, m_bhh, h0,
                        m_feat + (size_t)i*TT*32,
                        nh_out + (i >> 1)*96 + 32 + (i & 1)*32 + lane,
                        mask_f + (size_t)(b*TT)*2 + slot, lane);
    }
}

// ---------------- attention ------------------------------------------------
__global__ __launch_bounds__(256) void attn_kernel(
    const float* __restrict__ air_feat, const float* __restrict__ m_feat,
    const float* __restrict__ mask_f,
    const float* __restrict__ attn_in_w, const float* __restrict__ attn_in_b,
    const float* __restrict__ attn_out_w, const float* __restrict__ attn_out_b,
    float* __restrict__ attn_buf)
{
    int lane = threadIdx.x & 31;
    size_t n = (size_t)blockIdx.x*8 + (threadIdx.x >> 5);

    float wq[32], wk[32], wv[32], wo[32];
    #pragma unroll
    for (int k = 0; k < 32; k++) {
        wq[k] = attn_in_w[lane*32 + k];
        wk[k] = attn_in_w[(32+lane)*32 + k];
        wv[k] = attn_in_w[(64+lane)*32 + k];
        wo[k] = attn_out_w[lane*32 + k];
    }
    float bq = attn_in_b[lane], bk = attn_in_b[32+lane], bv = attn_in_b[64+lane];
    float bo = attn_out_b[lane];

    float a  = air_feat[n*32 + lane];
    float x1 = m_feat[n*32 + lane];
    float x2 = m_feat[(size_t)NN*32 + n*32 + lane];

    float q = bq, k1 = bk, k2 = bk, v1 = bv, v2 = bv;
    #pragma unroll
    for (int k = 0; k < 32; k++) {
        float av  = __shfl(a,  k, 32);
        float m1v = __shfl(x1, k, 32);
        float m2v = __shfl(x2, k, 32);
        q  += wq[k]*av;
        k1 += wk[k]*m1v; v1 += wv[k]*m1v;
        k2 += wk[k]*m2v; v2 += wv[k]*m2v;
    }
    float p1 = q*k1, p2 = q*k2;
    #pragma unroll
    for (int m = 1; m < 16; m <<= 1) {
        p1 += __shfl_xor(p1, m, 32);
        p2 += __shfl_xor(p2, m, 32);
    }
    bool msk0 = mask_f[n*2]   > 0.5f;
    bool msk1 = mask_f[n*2+1] > 0.5f;
    float s1 = p1*0.25f + (msk0 ? -1e9f : 0.f);
    float s2 = p2*0.25f + (msk1 ? -1e9f : 0.f);
    float mx = fmaxf(s1, s2);
    float e1 = __expf(s1 - mx), e2 = __expf(s2 - mx);
    float inv = 1.f/(e1 + e2);
    float ctx = (e1*v1 + e2*v2)*inv;

    float attn = bo;
    #pragma unroll
    for (int k = 0; k < 32; k++) attn += wo[k]*__shfl(ctx, k, 32);
    if (msk0 && msk1) attn = 0.f;
    attn_buf[n*32 + lane] = attn;
}

// ---------------- MLP ------------------------------------------------------
// tile M=32 positions per block; 256 threads as (tg 0..15)x(to 0..15);
// thread computes h of 2 rows x 16 outs.
__global__ __launch_bounds__(256) void mlp_kernel(
    const float* __restrict__ air_feat, const float* __restrict__ attn_buf,
    const float* __restrict__ W0T, const float* __restrict__ b0,
    const float* __restrict__ W1T, const float* __restrict__ b1,
    const float* __restrict__ outW, const float* __restrict__ outb,
    float* __restrict__ val)
{
    __shared__ float Fs[32*65];
    __shared__ float H1[32*260];
    __shared__ float red[32*17];

    int tid = threadIdx.x;
    size_t n0 = (size_t)blockIdx.x * 32;

    for (int idx = tid; idx < 32*64; idx += 256) {
        int m = idx >> 6, k = idx & 63;
        float v = (k < 32) ? air_feat[(n0+m)*32 + k] : attn_buf[(n0+m)*32 + (k-32)];
        Fs[m*65 + k] = v;
    }
    __syncthreads();

    int to = tid & 15, tg = tid >> 4;
    int m0 = tg*2;
    int ob = to*16;

    float acc0[16], acc1[16];
    #pragma unroll
    for (int u = 0; u < 16; u++) { acc0[u] = 0.f; acc1[u] = 0.f; }

    const float4* W0T4 = (const float4*)W0T;
    for (int k = 0; k < 64; k++) {
        float f0 = Fs[m0*65 + k];
        float f1 = Fs[m0*65 + 65 + k];
        const float4* wrow = W0T4 + (k*64 + (ob >> 2));
        #pragma unroll
        for (int uu = 0; uu < 4; uu++) {
            float4 w = wrow[uu];
            acc0[uu*4+0] += f0*w.x; acc0[uu*4+1] += f0*w.y;
            acc0[uu*4+2] += f0*w.z; acc0[uu*4+3] += f0*w.w;
            acc1[uu*4+0] += f1*w.x; acc1[uu*4+1] += f1*w.y;
            acc1[uu*4+2] += f1*w.z; acc1[uu*4+3] += f1*w.w;
        }
    }
    #pragma unroll
    for (int uu = 0; uu < 4; uu++) {
        float4 bb = ((const float4*)b0)[(ob >> 2) + uu];
        float bv[4] = {bb.x, bb.y, bb.z, bb.w};
        #pragma unroll
        for (int j = 0; j < 4; j++) {
            float h0v = acc0[uu*4+j] + bv[j];
            float h1v = acc1[uu*4+j] + bv[j];
            h0v = (h0v > 0.f) ? h0v : 0.01f*h0v;
            h1v = (h1v > 0.f) ? h1v : 0.01f*h1v;
            H1[m0*260 + ob + uu*4 + j]       = h0v;
            H1[(m0+1)*260 + ob + uu*4 + j]   = h1v;
        }
    }
    __syncthreads();

    #pragma unroll
    for (int u = 0; u < 16; u++) { acc0[u] = 0.f; acc1[u] = 0.f; }
    const float4* W1T4 = (const float4*)W1T;
    for (int k = 0; k < 256; k++) {
        float f0 = H1[m0*260 + k];
        float f1 = H1[m0*260 + 260 + k];
        const float4* wrow = W1T4 + (k*64 + (ob >> 2));
        #pragma unroll
        for (int uu = 0; uu < 4; uu++) {
            float4 w = wrow[uu];
            acc0[uu*4+0] += f0*w.x; acc0[uu*4+1] += f0*w.y;
            acc0[uu*4+2] += f0*w.z; acc0[uu*4+3] += f0*w.w;
            acc1[uu*4+0] += f1*w.x; acc1[uu*4+1] += f1*w.y;
            acc1[uu*4+2] += f1*w.z; acc1[uu*4+3] += f1*w.w;
        }
    }
    float pv0 = 0.f, pv1 = 0.f;
    #pragma unroll
    for (int uu = 0; uu < 4; uu++) {
        float4 bb = ((const float4*)b1)[(ob >> 2) + uu];
        float4 ow = ((const float4*)outW)[(ob >> 2) + uu];
        float bv[4] = {bb.x, bb.y, bb.z, bb.w};
        float wv2[4] = {ow.x, ow.y, ow.z, ow.w};
        #pragma unroll
        for (int j = 0; j < 4; j++) {
            float h0v = acc0[uu*4+j] + bv[j];
            float h1v = acc1[uu*4+j] + bv[j];
            h0v = (h0v > 0.f) ? h0v : 0.01f*h0v;
            h1v = (h1v > 0.f) ? h1v : 0.01f*h1v;
            pv0 += h0v*wv2[j];
            pv1 += h1v*wv2[j];
        }
    }
    red[m0*17 + to]     = pv0;
    red[(m0+1)*17 + to] = pv1;
    __syncthreads();
    if (tid < 32) {
        float s = outb[0];
        #pragma unroll
        for (int t2 = 0; t2 < 16; t2++) s += red[tid*17 + t2];
        val[n0 + tid] = s;
    }
}

// ---------------- launch ---------------------------------------------------
extern "C" void kernel_launch(void* const* d_in, const int* in_sizes, int n_in,
                              void* d_out, int out_size, void* d_ws, size_t ws_size,
                              hipStream_t stream) {
    const float* obs        = (const float*)d_in[0];
    const float* rnn        = (const float*)d_in[1];
    const float* enc_air_W  = (const float*)d_in[2];
    const float* enc_air_b  = (const float*)d_in[3];
    const float* enc_m_W    = (const float*)d_in[4];
    const float* enc_m_b    = (const float*)d_in[5];
    const float* air_Wih    = (const float*)d_in[6];
    const float* air_Whh    = (const float*)d_in[7];
    const float* air_bih    = (const float*)d_in[8];
    const float* air_bhh    = (const float*)d_in[9];
    const float* m_Wih      = (const float*)d_in[10];
    const float* m_Whh      = (const float*)d_in[11];
    const float* m_bih      = (const float*)d_in[12];
    const float* m_bhh      = (const float*)d_in[13];
    const float* attn_in_w  = (const float*)d_in[14];
    const float* attn_in_b  = (const float*)d_in[15];
    const float* attn_out_w = (const float*)d_in[16];
    const float* attn_out_b = (const float*)d_in[17];
    const float* mlp_W0     = (const float*)d_in[18];
    const float* mlp_b0     = (const float*)d_in[19];
    const float* mlp_W1     = (const float*)d_in[20];
    const float* mlp_b1     = (const float*)d_in[21];
    const float* out_W      = (const float*)d_in[22];
    const float* out_b      = (const float*)d_in[23];

    float* ws  = (float*)d_ws;
    float* out = (float*)d_out;

    prep_kernel<<<258, 256, 0, stream>>>(enc_air_W, enc_air_b, enc_m_W, enc_m_b,
                                         air_Wih, air_bih, m_Wih, m_bih,
                                         mlp_W0, mlp_W1, ws);

    gru_kernel<<<768, 256, 0, stream>>>(obs, rnn, ws,
                                        air_Whh, air_bhh, m_Whh, m_bhh,
                                        ws + OFF_AIRF, ws + OFF_MF, ws + OFF_MASK,
                                        out + NVAL);

    attn_kernel<<<NN/8, 256, 0, stream>>>(ws + OFF_AIRF, ws + OFF_MF, ws + OFF_MASK,
                                          attn_in_w, attn_in_b, attn_out_w, attn_out_b,
                                          ws + OFF_ATTN);

    mlp_kernel<<<NN/32, 256, 0, stream>>>(ws + OFF_AIRF, ws + OFF_ATTN,
                                          ws + OFF_W0T, mlp_b0,
                                          ws + OFF_W1T, mlp_b1,
                                          out_W, out_b, out);
}

// Round 2
// 952.602 us; speedup vs baseline: 3.1580x; 3.1580x over previous
//
#include <hip/hip_runtime.h>
#include <hip/hip_bf16.h>

#define BB 2048
#define TT 128
#define NN (BB*TT)          // 262144
#define NVAL NN

// workspace layout (float offsets)
#define OFF_WCA   0u          // 96x8 combined air input weights
#define OFF_BCA   768u        // 96
#define OFF_WCM   864u        // 96x8 combined m input weights
#define OFF_BCM   1632u       // 96
#define OFF_W0P   2048u       // 16384 bf16 = 8192 floats : W0 B-frag pack
#define OFF_W1P   10240u      // 65536 bf16 = 32768 floats: W1 B-frag pack
#define OFF_AIRF  83968u      // B*T*32 air_feat
#define OFF_MF    8472576u    // 2B*T*32 m_feat
#define OFF_MASK  25249792u   // N*2 mask floats
#define OFF_ATTN  25774080u   // N*32 attn output

typedef __attribute__((ext_vector_type(8))) short short8;
typedef __attribute__((ext_vector_type(4))) float f32x4;

__device__ __forceinline__ unsigned short f2bf(float f) {
    unsigned u = __builtin_bit_cast(unsigned, f);
    u += 0x7FFFu + ((u >> 16) & 1u);       // RNE
    return (unsigned short)(u >> 16);
}

// ---------------- prep -----------------------------------------------------
// b==0            : combined GRU input weights
// b in [1..32]    : w1pack (32*256*8 = 65536 bf16)
// b in [33..40]   : w0pack (8*256*8 = 16384 bf16)
__global__ __launch_bounds__(256) void prep_kernel(
    const float* __restrict__ enc_air_W, const float* __restrict__ enc_air_b,
    const float* __restrict__ enc_m_W,   const float* __restrict__ enc_m_b,
    const float* __restrict__ air_Wih,   const float* __restrict__ air_bih,
    const float* __restrict__ m_Wih,     const float* __restrict__ m_bih,
    const float* __restrict__ W0,        const float* __restrict__ W1,
    float* __restrict__ ws)
{
    int b = blockIdx.x, t = threadIdx.x;
    if (b == 0) {
        if (t < 96) {
            float bacc = air_bih[t];
            for (int i = 0; i < 7; i++) {
                float s = 0.f;
                for (int k = 0; k < 32; k++) s += air_Wih[t*32+k] * enc_air_W[k*7+i];
                ws[OFF_WCA + t*8 + i] = s;
            }
            for (int k = 0; k < 32; k++) bacc += air_Wih[t*32+k] * enc_air_b[k];
            ws[OFF_BCA + t] = bacc;

            float bacc2 = m_bih[t];
            for (int i = 0; i < 4; i++) {
                float s = 0.f;
                for (int k = 0; k < 32; k++) s += m_Wih[t*32+k] * enc_m_W[k*4+i];
                ws[OFF_WCM + t*8 + i] = s;
            }
            for (int k = 0; k < 32; k++) bacc2 += m_Wih[t*32+k] * enc_m_b[k];
            ws[OFF_BCM + t] = bacc2;
        }
    } else if (b <= 32) {
        // w1pack: idx base for this thread
        unsigned short* w1p = (unsigned short*)(ws + OFF_W1P);
        int base = ((b-1)*256 + t);          // frag slot (s,ct,lane)
        int lane = base & 63;
        int ctf  = base >> 6;                // s*16+ct
        int ct   = ctf & 15, s = ctf >> 4;   // s 0..7
        int col = lane & 15, quad = lane >> 4;
        int k0 = s*32 + quad*8;
        int o  = ct*16 + col;
        #pragma unroll
        for (int j = 0; j < 8; j++)
            w1p[base*8 + j] = f2bf(W1[o*256 + k0 + j]);
    } else if (b <= 40) {
        unsigned short* w0p = (unsigned short*)(ws + OFF_W0P);
        int base = ((b-33)*256 + t);
        int lane = base & 63;
        int ctf  = base >> 6;
        int ct   = ctf & 15, s = ctf >> 4;   // s 0..1
        int col = lane & 15, quad = lane >> 4;
        int k0 = s*32 + quad*8;
        int o  = ct*16 + col;
        #pragma unroll
        for (int j = 0; j < 8; j++)
            w0p[base*8 + j] = f2bf(W0[o*64 + k0 + j]);
    }
}

// ---------------- GRU ------------------------------------------------------
template<int NI, bool DO_MASK>
__device__ void gru_row(const float* __restrict__ in_base,
                        const float* __restrict__ Wc,
                        const float* __restrict__ bc,
                        const float* __restrict__ Whh,
                        const float* __restrict__ bhh,
                        float h0,
                        float* __restrict__ feat_out,
                        float* __restrict__ hT_out,
                        float* __restrict__ mask_out,
                        int lane)
{
    float wr[32], wz[32], wn[32];
    #pragma unroll
    for (int k = 0; k < 32; k++) {
        wr[k] = Whh[lane*32 + k];
        wz[k] = Whh[(32+lane)*32 + k];
        wn[k] = Whh[(64+lane)*32 + k];
    }
    float cr[NI], cz[NI], cn[NI];
    #pragma unroll
    for (int i = 0; i < NI; i++) {
        cr[i] = Wc[lane*8 + i];
        cz[i] = Wc[(32+lane)*8 + i];
        cn[i] = Wc[(64+lane)*8 + i];
    }
    const float bcr = bc[lane], bcz = bc[32+lane], bcn = bc[64+lane];
    const float bhr = bhh[lane], bhz = bhh[32+lane], bhn = bhh[64+lane];

    float h = h0;
    for (int t = 0; t < TT; t++) {
        float xin = (lane < NI) ? in_base[t*15 + lane] : 0.f;
        float ar = bcr, az = bcz, an = bcn;
        bool ok = true;
        #pragma unroll
        for (int i = 0; i < NI; i++) {
            float v = __shfl(xin, i, 32);
            ar += cr[i]*v; az += cz[i]*v; an += cn[i]*v;
            if (DO_MASK) {
                const float c   = ((i & 1) == 0) ? 1.f : 0.f;
                const float thr = ((i & 1) == 0) ? 1.00001e-5f : 1e-8f;
                ok = ok & (fabsf(v - c) <= thr);
            }
        }
        float hr = bhr, hz = bhz, hn = bhn;
        #pragma unroll
        for (int k = 0; k < 32; k++) {
            float hv = __shfl(h, k, 32);
            hr += wr[k]*hv; hz += wz[k]*hv; hn += wn[k]*hv;
        }
        float r = 1.f / (1.f + __expf(-(ar + hr)));
        float z = 1.f / (1.f + __expf(-(az + hz)));
        float pre = an + r*hn;
        float e2 = __expf(2.f*pre);
        float n = 1.f - 2.f/(e2 + 1.f);
        h = n + z*(h - n);
        feat_out[t*32 + lane] = h;
        if (DO_MASK) {
            if (lane == 0) mask_out[t*2] = ok ? 1.f : 0.f;
        }
    }
    *hT_out = h;
}

__global__ __launch_bounds__(256) void gru_kernel(
    const float* __restrict__ obs, const float* __restrict__ rnn,
    const float* __restrict__ ws_c,
    const float* __restrict__ air_Whh, const float* __restrict__ air_bhh,
    const float* __restrict__ m_Whh,   const float* __restrict__ m_bhh,
    float* __restrict__ air_feat, float* __restrict__ m_feat,
    float* __restrict__ mask_f, float* __restrict__ nh_out)
{
    int lane = threadIdx.x & 31;
    int r = blockIdx.x*8 + (threadIdx.x >> 5);
    if (r < BB) {
        const float* in_base = obs + r*(TT*15) + 8;
        float h0 = rnn[r*96 + lane];
        gru_row<7,false>(in_base, ws_c + OFF_WCA, ws_c + OFF_BCA,
                         air_Whh, air_bhh, h0,
                         air_feat + (size_t)r*TT*32,
                         nh_out + r*96 + lane, nullptr, lane);
    } else {
        int i = r - BB;
        int b = (i < BB) ? i : i - BB;
        int slot = (i < BB) ? 0 : 1;
        const float* in_base = obs + b*(TT*15) + slot*4;
        float h0 = rnn[(i >> 1)*96 + 32 + (i & 1)*32 + lane];
        gru_row<4,true>(in_base, ws_c + OFF_WCM, ws_c + OFF_BCM,
                        m_Whh, m_bhh, h0,
                        m_feat + (size_t)i*TT*32,
                        nh_out + (i >> 1)*96 + 32 + (i & 1)*32 + lane,
                        mask_f + (size_t)(b*TT)*2 + slot, lane);
    }
}

// ---------------- attention ------------------------------------------------
__global__ __launch_bounds__(256) void attn_kernel(
    const float* __restrict__ air_feat, const float* __restrict__ m_feat,
    const float* __restrict__ mask_f,
    const float* __restrict__ attn_in_w, const float* __restrict__ attn_in_b,
    const float* __restrict__ attn_out_w, const float* __restrict__ attn_out_b,
    float* __restrict__ attn_buf)
{
    int lane = threadIdx.x & 31;
    size_t n = (size_t)blockIdx.x*8 + (threadIdx.x >> 5);

    float wq[32], wk[32], wv[32], wo[32];
    #pragma unroll
    for (int k = 0; k < 32; k++) {
        wq[k] = attn_in_w[lane*32 + k];
        wk[k] = attn_in_w[(32+lane)*32 + k];
        wv[k] = attn_in_w[(64+lane)*32 + k];
        wo[k] = attn_out_w[lane*32 + k];
    }
    float bq = attn_in_b[lane], bk = attn_in_b[32+lane], bv = attn_in_b[64+lane];
    float bo = attn_out_b[lane];

    float a  = air_feat[n*32 + lane];
    float x1 = m_feat[n*32 + lane];
    float x2 = m_feat[(size_t)NN*32 + n*32 + lane];

    float q = bq, k1 = bk, k2 = bk, v1 = bv, v2 = bv;
    #pragma unroll
    for (int k = 0; k < 32; k++) {
        float av  = __shfl(a,  k, 32);
        float m1v = __shfl(x1, k, 32);
        float m2v = __shfl(x2, k, 32);
        q  += wq[k]*av;
        k1 += wk[k]*m1v; v1 += wv[k]*m1v;
        k2 += wk[k]*m2v; v2 += wv[k]*m2v;
    }
    float p1 = q*k1, p2 = q*k2;
    #pragma unroll
    for (int m = 1; m < 16; m <<= 1) {
        p1 += __shfl_xor(p1, m, 32);
        p2 += __shfl_xor(p2, m, 32);
    }
    bool msk0 = mask_f[n*2]   > 0.5f;
    bool msk1 = mask_f[n*2+1] > 0.5f;
    float s1 = p1*0.25f + (msk0 ? -1e9f : 0.f);
    float s2 = p2*0.25f + (msk1 ? -1e9f : 0.f);
    float mx = fmaxf(s1, s2);
    float e1 = __expf(s1 - mx), e2 = __expf(s2 - mx);
    float inv = 1.f/(e1 + e2);
    float ctx = (e1*v1 + e2*v2)*inv;

    float attn = bo;
    #pragma unroll
    for (int k = 0; k < 32; k++) attn += wo[k]*__shfl(ctx, k, 32);
    if (msk0 && msk1) attn = 0.f;
    attn_buf[n*32 + lane] = attn;
}

// ---------------- MLP: bf16 MFMA -------------------------------------------
// 64 rows/block, 4 waves; wave w owns row-strip [w*16, w*16+16), all 16
// col-tiles. LDS: A1 = fusion bf16 [64][72] (pad 8 -> 2-way bank alias,
// free); A2 = h1 bf16 [64][264].
__global__ __launch_bounds__(256) void mlp_kernel(
    const float* __restrict__ air_feat, const float* __restrict__ attn_buf,
    const unsigned short* __restrict__ w0p, const float* __restrict__ b0,
    const unsigned short* __restrict__ w1p, const float* __restrict__ b1,
    const float* __restrict__ outW, const float* __restrict__ outb,
    float* __restrict__ val)
{
    __shared__ unsigned short A1[64*72];
    __shared__ unsigned short A2[64*264];

    const int tid  = threadIdx.x;
    const int lane = tid & 63;
    const int strip = tid >> 6;            // wave id
    const int col  = lane & 15;
    const int quad = lane >> 4;
    const size_t n0 = (size_t)blockIdx.x * 64;

    // ---- stage fusion tile (64 rows x 64 cols fp32 -> bf16 LDS) ----
    {
        const float4* air4 = (const float4*)air_feat;
        const float4* att4 = (const float4*)attn_buf;
        #pragma unroll
        for (int i = 0; i < 4; i++) {
            int f4 = tid + i*256;              // 0..1023
            int row = f4 >> 4;
            int c4  = f4 & 15;
            float4 v = (c4 < 8) ? air4[(n0+row)*8 + c4]
                                : att4[(n0+row)*8 + (c4-8)];
            ushort4 o;
            o.x = f2bf(v.x); o.y = f2bf(v.y); o.z = f2bf(v.z); o.w = f2bf(v.w);
            *(ushort4*)&A1[row*72 + c4*4] = o;
        }
    }
    __syncthreads();

    // per-lane bias / out-weight preloads (col-indexed)
    float b0r[16], b1r[16], owr[16];
    #pragma unroll
    for (int ct = 0; ct < 16; ct++) {
        b0r[ct] = b0[ct*16 + col];
        b1r[ct] = b1[ct*16 + col];
        owr[ct] = outW[ct*16 + col];
    }
    const float outb0 = outb[0];

    // ---- layer 1: [64] -> [256], K=64 (2 k-steps) ----
    f32x4 acc1[16];
    #pragma unroll
    for (int ct = 0; ct < 16; ct++) acc1[ct] = (f32x4){0.f,0.f,0.f,0.f};

    #pragma unroll
    for (int ks = 0; ks < 2; ks++) {
        short8 a = *(const short8*)&A1[(strip*16 + col)*72 + ks*32 + quad*8];
        #pragma unroll
        for (int ct = 0; ct < 16; ct++) {
            short8 bfr = *(const short8*)(w0p + ((ks*16 + ct)*64 + lane)*8);
            acc1[ct] = __builtin_amdgcn_mfma_f32_16x16x32_bf16(a, bfr, acc1[ct], 0, 0, 0);
        }
    }
    // epilogue: bias + leaky-relu -> bf16 -> A2 (rows of own strip only)
    #pragma unroll
    for (int ct = 0; ct < 16; ct++) {
        #pragma unroll
        for (int reg = 0; reg < 4; reg++) {
            float h = acc1[ct][reg] + b0r[ct];
            h = (h > 0.f) ? h : 0.01f*h;
            A2[(strip*16 + quad*4 + reg)*264 + ct*16 + col] = f2bf(h);
        }
    }
    // no __syncthreads needed: each wave reads back only rows it wrote
    // (intra-wave lgkmcnt dependency handled by compiler)

    // ---- layer 2: [256] -> [256], K=256 (8 k-steps) ----
    f32x4 acc2[16];
    #pragma unroll
    for (int ct = 0; ct < 16; ct++) acc2[ct] = (f32x4){0.f,0.f,0.f,0.f};

    for (int ks = 0; ks < 8; ks++) {
        short8 a = *(const short8*)&A2[(strip*16 + col)*264 + ks*32 + quad*8];
        #pragma unroll
        for (int ct = 0; ct < 16; ct++) {
            short8 bfr = *(const short8*)(w1p + ((ks*16 + ct)*64 + lane)*8);
            acc2[ct] = __builtin_amdgcn_mfma_f32_16x16x32_bf16(a, bfr, acc2[ct], 0, 0, 0);
        }
    }

    // ---- out layer: bias + lrelu, dot with outW, reduce over cols ----
    float pv0 = 0.f, pv1 = 0.f, pv2 = 0.f, pv3 = 0.f;
    #pragma unroll
    for (int ct = 0; ct < 16; ct++) {
        float h0v = acc2[ct][0] + b1r[ct]; h0v = (h0v > 0.f) ? h0v : 0.01f*h0v;
        float h1v = acc2[ct][1] + b1r[ct]; h1v = (h1v > 0.f) ? h1v : 0.01f*h1v;
        float h2v = acc2[ct][2] + b1r[ct]; h2v = (h2v > 0.f) ? h2v : 0.01f*h2v;
        float h3v = acc2[ct][3] + b1r[ct]; h3v = (h3v > 0.f) ? h3v : 0.01f*h3v;
        pv0 += h0v*owr[ct]; pv1 += h1v*owr[ct];
        pv2 += h2v*owr[ct]; pv3 += h3v*owr[ct];
    }
    #pragma unroll
    for (int m = 1; m < 16; m <<= 1) {
        pv0 += __shfl_xor(pv0, m, 64);
        pv1 += __shfl_xor(pv1, m, 64);
        pv2 += __shfl_xor(pv2, m, 64);
        pv3 += __shfl_xor(pv3, m, 64);
    }
    if (col == 0) {
        size_t rbase = n0 + strip*16 + quad*4;
        val[rbase + 0] = pv0 + outb0;
        val[rbase + 1] = pv1 + outb0;
        val[rbase + 2] = pv2 + outb0;
        val[rbase + 3] = pv3 + outb0;
    }
}

// ---------------- launch ---------------------------------------------------
extern "C" void kernel_launch(void* const* d_in, const int* in_sizes, int n_in,
                              void* d_out, int out_size, void* d_ws, size_t ws_size,
                              hipStream_t stream) {
    const float* obs        = (const float*)d_in[0];
    const float* rnn        = (const float*)d_in[1];
    const float* enc_air_W  = (const float*)d_in[2];
    const float* enc_air_b  = (const float*)d_in[3];
    const float* enc_m_W    = (const float*)d_in[4];
    const float* enc_m_b    = (const float*)d_in[5];
    const float* air_Wih    = (const float*)d_in[6];
    const float* air_Whh    = (const float*)d_in[7];
    const float* air_bih    = (const float*)d_in[8];
    const float* air_bhh    = (const float*)d_in[9];
    const float* m_Wih      = (const float*)d_in[10];
    const float* m_Whh      = (const float*)d_in[11];
    const float* m_bih      = (const float*)d_in[12];
    const float* m_bhh      = (const float*)d_in[13];
    const float* attn_in_w  = (const float*)d_in[14];
    const float* attn_in_b  = (const float*)d_in[15];
    const float* attn_out_w = (const float*)d_in[16];
    const float* attn_out_b = (const float*)d_in[17];
    const float* mlp_W0     = (const float*)d_in[18];
    const float* mlp_b0     = (const float*)d_in[19];
    const float* mlp_W1     = (const float*)d_in[20];
    const float* mlp_b1     = (const float*)d_in[21];
    const float* out_W      = (const float*)d_in[22];
    const float* out_b      = (const float*)d_in[23];

    float* ws  = (float*)d_ws;
    float* out = (float*)d_out;

    prep_kernel<<<41, 256, 0, stream>>>(enc_air_W, enc_air_b, enc_m_W, enc_m_b,
                                        air_Wih, air_bih, m_Wih, m_bih,
                                        mlp_W0, mlp_W1, ws);

    gru_kernel<<<768, 256, 0, stream>>>(obs, rnn, ws,
                                        air_Whh, air_bhh, m_Whh, m_bhh,
                                        ws + OFF_AIRF, ws + OFF_MF, ws + OFF_MASK,
                                        out + NVAL);

    attn_kernel<<<NN/8, 256, 0, stream>>>(ws + OFF_AIRF, ws + OFF_MF, ws + OFF_MASK,
                                          attn_in_w, attn_in_b, attn_out_w, attn_out_b,
                                          ws + OFF_ATTN);

    mlp_kernel<<<NN/64, 256, 0, stream>>>(ws + OFF_AIRF, ws + OFF_ATTN,
                                          (const unsigned short*)(ws + OFF_W0P), mlp_b0,
                                          (const unsigned short*)(ws + OFF_W1P), mlp_b1,
                                          out_W, out_b, out);
}

// Round 3
// 452.677 us; speedup vs baseline: 6.6457x; 2.1044x over previous
//
#include <hip/hip_runtime.h>
#include <hip/hip_bf16.h>

#define BB 2048
#define TT 128
#define NN (BB*TT)          // 262144
#define NVAL NN

// workspace layout (float offsets)
#define OFF_WCA   0u          // 96x8 combined air input weights
#define OFF_BCA   768u        // 96
#define OFF_WCM   864u        // 96x8 combined m input weights
#define OFF_BCM   1632u       // 96
#define OFF_W0P   2048u       // 16384 bf16 = 8192 floats : W0 B-frag pack
#define OFF_W1P   10240u      // 65536 bf16 = 32768 floats: W1 B-frag pack
#define OFF_WQKV  43008u      // 3072 bf16 = 1536 floats : attn_in_w B-frag pack
#define OFF_WO    44544u      // 1024 bf16 = 512 floats  : attn_out_w B-frag pack
#define OFF_AIRF  83968u      // B*T*32 air_feat
#define OFF_MF    8472576u    // 2B*T*32 m_feat
#define OFF_MASK  25249792u   // N*2 mask floats

typedef __attribute__((ext_vector_type(8))) short short8;
typedef __attribute__((ext_vector_type(4))) float f32x4;

__device__ __forceinline__ unsigned short f2bf(float f) {
    unsigned u = __builtin_bit_cast(unsigned, f);
    u += 0x7FFFu + ((u >> 16) & 1u);       // RNE
    return (unsigned short)(u >> 16);
}

// ---------------- prep -----------------------------------------------------
__global__ __launch_bounds__(256) void prep_kernel(
    const float* __restrict__ enc_air_W, const float* __restrict__ enc_air_b,
    const float* __restrict__ enc_m_W,   const float* __restrict__ enc_m_b,
    const float* __restrict__ air_Wih,   const float* __restrict__ air_bih,
    const float* __restrict__ m_Wih,     const float* __restrict__ m_bih,
    const float* __restrict__ W0,        const float* __restrict__ W1,
    const float* __restrict__ attn_in_w, const float* __restrict__ attn_out_w,
    float* __restrict__ ws)
{
    int b = blockIdx.x, t = threadIdx.x;
    if (b == 0) {
        if (t < 96) {
            float bacc = air_bih[t];
            for (int i = 0; i < 7; i++) {
                float s = 0.f;
                for (int k = 0; k < 32; k++) s += air_Wih[t*32+k] * enc_air_W[k*7+i];
                ws[OFF_WCA + t*8 + i] = s;
            }
            for (int k = 0; k < 32; k++) bacc += air_Wih[t*32+k] * enc_air_b[k];
            ws[OFF_BCA + t] = bacc;

            float bacc2 = m_bih[t];
            for (int i = 0; i < 4; i++) {
                float s = 0.f;
                for (int k = 0; k < 32; k++) s += m_Wih[t*32+k] * enc_m_W[k*4+i];
                ws[OFF_WCM + t*8 + i] = s;
            }
            for (int k = 0; k < 32; k++) bacc2 += m_Wih[t*32+k] * enc_m_b[k];
            ws[OFF_BCM + t] = bacc2;
        }
    } else if (b <= 32) {
        unsigned short* w1p = (unsigned short*)(ws + OFF_W1P);
        int base = ((b-1)*256 + t);
        int lane = base & 63;
        int ctf  = base >> 6;
        int ct   = ctf & 15, s = ctf >> 4;   // s 0..7
        int col = lane & 15, quad = lane >> 4;
        int k0 = s*32 + quad*8;
        int o  = ct*16 + col;
        #pragma unroll
        for (int j = 0; j < 8; j++)
            w1p[base*8 + j] = f2bf(W1[o*256 + k0 + j]);
    } else if (b <= 40) {
        unsigned short* w0p = (unsigned short*)(ws + OFF_W0P);
        int base = ((b-33)*256 + t);
        int lane = base & 63;
        int ctf  = base >> 6;
        int ct   = ctf & 15, s = ctf >> 4;   // s 0..1
        int col = lane & 15, quad = lane >> 4;
        int k0 = s*32 + quad*8;
        int o  = ct*16 + col;
        #pragma unroll
        for (int j = 0; j < 8; j++)
            w0p[base*8 + j] = f2bf(W0[o*64 + k0 + j]);
    } else { // b == 41: attention weight packs (K=32, single k-step)
        unsigned short* wqkv = (unsigned short*)(ws + OFF_WQKV);
        unsigned short* wop  = (unsigned short*)(ws + OFF_WO);
        for (int slot = t; slot < 512; slot += 256) {
            if (slot < 384) {
                int ct = slot >> 6, lane = slot & 63;
                int col = lane & 15, quad = lane >> 4;
                int o = ct*16 + col;                 // 0..95 across q,k,v
                #pragma unroll
                for (int j = 0; j < 8; j++)
                    wqkv[slot*8 + j] = f2bf(attn_in_w[o*32 + quad*8 + j]);
            } else {
                int s2 = slot - 384;
                int ct = s2 >> 6, lane = s2 & 63;
                int col = lane & 15, quad = lane >> 4;
                #pragma unroll
                for (int j = 0; j < 8; j++)
                    wop[s2*8 + j] = f2bf(attn_out_w[(ct*16+col)*32 + quad*8 + j]);
            }
        }
    }
}

// ---------------- GRU ------------------------------------------------------
template<int NI, bool DO_MASK>
__device__ void gru_row(const float* __restrict__ in_base,
                        const float* __restrict__ Wc,
                        const float* __restrict__ bc,
                        const float* __restrict__ Whh,
                        const float* __restrict__ bhh,
                        float h0,
                        float* __restrict__ feat_out,
                        float* __restrict__ hT_out,
                        float* __restrict__ mask_out,
                        int lane)
{
    float wr[32], wz[32], wn[32];
    #pragma unroll
    for (int k = 0; k < 32; k++) {
        wr[k] = Whh[lane*32 + k];
        wz[k] = Whh[(32+lane)*32 + k];
        wn[k] = Whh[(64+lane)*32 + k];
    }
    float cr[NI], cz[NI], cn[NI];
    #pragma unroll
    for (int i = 0; i < NI; i++) {
        cr[i] = Wc[lane*8 + i];
        cz[i] = Wc[(32+lane)*8 + i];
        cn[i] = Wc[(64+lane)*8 + i];
    }
    const float bcr = bc[lane], bcz = bc[32+lane], bcn = bc[64+lane];
    const float bhr = bhh[lane], bhz = bhh[32+lane], bhn = bhh[64+lane];

    float h = h0;
    for (int t = 0; t < TT; t++) {
        float xin = (lane < NI) ? in_base[t*15 + lane] : 0.f;
        float ar = bcr, az = bcz, an = bcn;
        bool ok = true;
        #pragma unroll
        for (int i = 0; i < NI; i++) {
            float v = __shfl(xin, i, 32);
            ar += cr[i]*v; az += cz[i]*v; an += cn[i]*v;
            if (DO_MASK) {
                const float c   = ((i & 1) == 0) ? 1.f : 0.f;
                const float thr = ((i & 1) == 0) ? 1.00001e-5f : 1e-8f;
                ok = ok & (fabsf(v - c) <= thr);
            }
        }
        float hr = bhr, hz = bhz, hn = bhn;
        #pragma unroll
        for (int k = 0; k < 32; k++) {
            float hv = __shfl(h, k, 32);
            hr += wr[k]*hv; hz += wz[k]*hv; hn += wn[k]*hv;
        }
        float r = 1.f / (1.f + __expf(-(ar + hr)));
        float z = 1.f / (1.f + __expf(-(az + hz)));
        float pre = an + r*hn;
        float e2 = __expf(2.f*pre);
        float n = 1.f - 2.f/(e2 + 1.f);
        h = n + z*(h - n);
        feat_out[t*32 + lane] = h;
        if (DO_MASK) {
            if (lane == 0) mask_out[t*2] = ok ? 1.f : 0.f;
        }
    }
    *hT_out = h;
}

__global__ __launch_bounds__(256) void gru_kernel(
    const float* __restrict__ obs, const float* __restrict__ rnn,
    const float* __restrict__ ws_c,
    const float* __restrict__ air_Whh, const float* __restrict__ air_bhh,
    const float* __restrict__ m_Whh,   const float* __restrict__ m_bhh,
    float* __restrict__ air_feat, float* __restrict__ m_feat,
    float* __restrict__ mask_f, float* __restrict__ nh_out)
{
    int lane = threadIdx.x & 31;
    int r = blockIdx.x*8 + (threadIdx.x >> 5);
    if (r < BB) {
        const float* in_base = obs + r*(TT*15) + 8;
        float h0 = rnn[r*96 + lane];
        gru_row<7,false>(in_base, ws_c + OFF_WCA, ws_c + OFF_BCA,
                         air_Whh, air_bhh, h0,
                         air_feat + (size_t)r*TT*32,
                         nh_out + r*96 + lane, nullptr, lane);
    } else {
        int i = r - BB;
        int b = (i < BB) ? i : i - BB;
        int slot = (i < BB) ? 0 : 1;
        const float* in_base = obs + b*(TT*15) + slot*4;
        float h0 = rnn[(i >> 1)*96 + 32 + (i & 1)*32 + lane];
        gru_row<4,true>(in_base, ws_c + OFF_WCM, ws_c + OFF_BCM,
                        m_Whh, m_bhh, h0,
                        m_feat + (size_t)i*TT*32,
                        nh_out + (i >> 1)*96 + 32 + (i & 1)*32 + lane,
                        mask_f + (size_t)(b*TT)*2 + slot, lane);
    }
}

// ---------------- fused attention + MLP (bf16 MFMA) -------------------------
// 64 rows/block, 4 waves; wave w owns row-strip [w*16, w*16+16).
__global__ __launch_bounds__(256) void fused_kernel(
    const float* __restrict__ air_feat, const float* __restrict__ m_feat,
    const float* __restrict__ mask_f,
    const unsigned short* __restrict__ wqkv, const float* __restrict__ attn_in_b,
    const unsigned short* __restrict__ wop,  const float* __restrict__ attn_out_b,
    const unsigned short* __restrict__ w0p, const float* __restrict__ b0,
    const unsigned short* __restrict__ w1p, const float* __restrict__ b1,
    const float* __restrict__ outW, const float* __restrict__ outb,
    float* __restrict__ val)
{
    __shared__ unsigned short A1[64*72];   // fusion: air cols 0-31, attn cols 32-63
    __shared__ unsigned short AM[64*72];   // m1 cols 0-31, m2 cols 32-63
    __shared__ unsigned short CT[64*40];   // ctx round-trip (C-layout -> A-frag)
    __shared__ unsigned short A2[64*264];  // h1
    __shared__ float MS[128];              // masks: 2 per row

    const int tid  = threadIdx.x;
    const int lane = tid & 63;
    const int strip = tid >> 6;
    const int col  = lane & 15;
    const int quad = lane >> 4;
    const size_t n0 = (size_t)blockIdx.x * 64;

    // ---- stage: air, m1, m2 (fp32 -> bf16 LDS A-layout) + masks ----
    {
        const float4* air4 = (const float4*)air_feat;
        const float4* mf4  = (const float4*)m_feat;
        #pragma unroll
        for (int i = 0; i < 2; i++) {
            int f4 = tid + i*256;          // 0..511
            int row = f4 >> 3, c4 = f4 & 7;
            float4 v = air4[(n0+row)*8 + c4];
            ushort4 o; o.x=f2bf(v.x); o.y=f2bf(v.y); o.z=f2bf(v.z); o.w=f2bf(v.w);
            *(ushort4*)&A1[row*72 + c4*4] = o;
        }
        #pragma unroll
        for (int i = 0; i < 2; i++) {
            int f4 = tid + i*256;
            int row = f4 >> 3, c4 = f4 & 7;
            float4 v = mf4[(n0+row)*8 + c4];
            ushort4 o; o.x=f2bf(v.x); o.y=f2bf(v.y); o.z=f2bf(v.z); o.w=f2bf(v.w);
            *(ushort4*)&AM[row*72 + c4*4] = o;
        }
        #pragma unroll
        for (int i = 0; i < 2; i++) {
            int f4 = tid + i*256;
            int row = f4 >> 3, c4 = f4 & 7;
            float4 v = mf4[((size_t)NN + n0 + row)*8 + c4];
            ushort4 o; o.x=f2bf(v.x); o.y=f2bf(v.y); o.z=f2bf(v.z); o.w=f2bf(v.w);
            *(ushort4*)&AM[row*72 + 32 + c4*4] = o;
        }
        if (tid < 128) MS[tid] = mask_f[n0*2 + tid];
    }
    __syncthreads();

    // ---- attention (wave-local 16-row strip) ----
    {
        short8 a_air = *(const short8*)&A1[(strip*16 + col)*72 + quad*8];
        short8 a_m1  = *(const short8*)&AM[(strip*16 + col)*72 + quad*8];
        short8 a_m2  = *(const short8*)&AM[(strip*16 + col)*72 + 32 + quad*8];

        f32x4 q[2], k1[2], k2[2], v1[2], v2[2], ao[2];
        #pragma unroll
        for (int ct = 0; ct < 2; ct++) {
            f32x4 z = (f32x4){0.f,0.f,0.f,0.f};
            short8 wqf = *(const short8*)(wqkv + ((0+ct)*64 + lane)*8);
            short8 wkf = *(const short8*)(wqkv + ((2+ct)*64 + lane)*8);
            short8 wvf = *(const short8*)(wqkv + ((4+ct)*64 + lane)*8);
            q[ct]  = __builtin_amdgcn_mfma_f32_16x16x32_bf16(a_air, wqf, z, 0,0,0);
            k1[ct] = __builtin_amdgcn_mfma_f32_16x16x32_bf16(a_m1,  wkf, z, 0,0,0);
            k2[ct] = __builtin_amdgcn_mfma_f32_16x16x32_bf16(a_m2,  wkf, z, 0,0,0);
            v1[ct] = __builtin_amdgcn_mfma_f32_16x16x32_bf16(a_m1,  wvf, z, 0,0,0);
            v2[ct] = __builtin_amdgcn_mfma_f32_16x16x32_bf16(a_m2,  wvf, z, 0,0,0);
        }
        // biases (per output col)
        float bqr[2], bkr[2], bvr[2];
        #pragma unroll
        for (int ct = 0; ct < 2; ct++) {
            bqr[ct] = attn_in_b[ct*16 + col];
            bkr[ct] = attn_in_b[32 + ct*16 + col];
            bvr[ct] = attn_in_b[64 + ct*16 + col];
        }
        // scores: per (ct=head, reg=row) dot over 16 col-lanes
        float p1s[2][4], p2s[2][4];
        #pragma unroll
        for (int ct = 0; ct < 2; ct++) {
            #pragma unroll
            for (int reg = 0; reg < 4; reg++) {
                float qq = q[ct][reg] + bqr[ct];
                float p1 = qq * (k1[ct][reg] + bkr[ct]);
                float p2 = qq * (k2[ct][reg] + bkr[ct]);
                #pragma unroll
                for (int m = 1; m < 16; m <<= 1) {
                    p1 += __shfl_xor(p1, m, 64);
                    p2 += __shfl_xor(p2, m, 64);
                }
                p1s[ct][reg] = p1; p2s[ct][reg] = p2;
            }
        }
        // softmax + ctx -> CT (bf16, C-layout rows)
        float bothm[4];
        #pragma unroll
        for (int reg = 0; reg < 4; reg++) {
            int rloc = strip*16 + quad*4 + reg;
            float m0v = MS[rloc*2], m1v = MS[rloc*2 + 1];
            bothm[reg] = (m0v > 0.5f && m1v > 0.5f) ? 1.f : 0.f;
            #pragma unroll
            for (int ct = 0; ct < 2; ct++) {
                float s1 = p1s[ct][reg]*0.25f + (m0v > 0.5f ? -1e9f : 0.f);
                float s2 = p2s[ct][reg]*0.25f + (m1v > 0.5f ? -1e9f : 0.f);
                float mx = fmaxf(s1, s2);
                float e1 = __expf(s1 - mx), e2 = __expf(s2 - mx);
                float inv = 1.f/(e1 + e2);
                float ctxv = ((v1[ct][reg] + bvr[ct])*e1 +
                              (v2[ct][reg] + bvr[ct])*e2) * inv;
                CT[rloc*40 + ct*16 + col] = f2bf(ctxv);
            }
        }
        // out-proj: ctx (A-frag) x Wo^T
        short8 a_ctx = *(const short8*)&CT[(strip*16 + col)*40 + quad*8];
        #pragma unroll
        for (int ct = 0; ct < 2; ct++) {
            f32x4 z = (f32x4){0.f,0.f,0.f,0.f};
            short8 wof = *(const short8*)(wop + (ct*64 + lane)*8);
            ao[ct] = __builtin_amdgcn_mfma_f32_16x16x32_bf16(a_ctx, wof, z, 0,0,0);
        }
        float bor[2] = { attn_out_b[col], attn_out_b[16 + col] };
        #pragma unroll
        for (int reg = 0; reg < 4; reg++) {
            int rloc = strip*16 + quad*4 + reg;
            #pragma unroll
            for (int ct = 0; ct < 2; ct++) {
                float av = ao[ct][reg] + bor[ct];
                av = (bothm[reg] > 0.5f) ? 0.f : av;
                A1[rloc*72 + 32 + ct*16 + col] = f2bf(av);
            }
        }
    }

    // per-lane bias / out-weight preloads for MLP
    float b0r[16], b1r[16], owr[16];
    #pragma unroll
    for (int ct = 0; ct < 16; ct++) {
        b0r[ct] = b0[ct*16 + col];
        b1r[ct] = b1[ct*16 + col];
        owr[ct] = outW[ct*16 + col];
    }
    const float outb0 = outb[0];

    // ---- layer 1: [64] -> [256], K=64 ----
    f32x4 acc1[16];
    #pragma unroll
    for (int ct = 0; ct < 16; ct++) acc1[ct] = (f32x4){0.f,0.f,0.f,0.f};

    #pragma unroll
    for (int ks = 0; ks < 2; ks++) {
        short8 a = *(const short8*)&A1[(strip*16 + col)*72 + ks*32 + quad*8];
        #pragma unroll
        for (int ct = 0; ct < 16; ct++) {
            short8 bfr = *(const short8*)(w0p + ((ks*16 + ct)*64 + lane)*8);
            acc1[ct] = __builtin_amdgcn_mfma_f32_16x16x32_bf16(a, bfr, acc1[ct], 0, 0, 0);
        }
    }
    #pragma unroll
    for (int ct = 0; ct < 16; ct++) {
        #pragma unroll
        for (int reg = 0; reg < 4; reg++) {
            float h = acc1[ct][reg] + b0r[ct];
            h = (h > 0.f) ? h : 0.01f*h;
            A2[(strip*16 + quad*4 + reg)*264 + ct*16 + col] = f2bf(h);
        }
    }

    // ---- layer 2: [256] -> [256], K=256 ----
    f32x4 acc2[16];
    #pragma unroll
    for (int ct = 0; ct < 16; ct++) acc2[ct] = (f32x4){0.f,0.f,0.f,0.f};

    for (int ks = 0; ks < 8; ks++) {
        short8 a = *(const short8*)&A2[(strip*16 + col)*264 + ks*32 + quad*8];
        #pragma unroll
        for (int ct = 0; ct < 16; ct++) {
            short8 bfr = *(const short8*)(w1p + ((ks*16 + ct)*64 + lane)*8);
            acc2[ct] = __builtin_amdgcn_mfma_f32_16x16x32_bf16(a, bfr, acc2[ct], 0, 0, 0);
        }
    }

    // ---- out layer ----
    float pv0 = 0.f, pv1 = 0.f, pv2 = 0.f, pv3 = 0.f;
    #pragma unroll
    for (int ct = 0; ct < 16; ct++) {
        float h0v = acc2[ct][0] + b1r[ct]; h0v = (h0v > 0.f) ? h0v : 0.01f*h0v;
        float h1v = acc2[ct][1] + b1r[ct]; h1v = (h1v > 0.f) ? h1v : 0.01f*h1v;
        float h2v = acc2[ct][2] + b1r[ct]; h2v = (h2v > 0.f) ? h2v : 0.01f*h2v;
        float h3v = acc2[ct][3] + b1r[ct]; h3v = (h3v > 0.f) ? h3v : 0.01f*h3v;
        pv0 += h0v*owr[ct]; pv1 += h1v*owr[ct];
        pv2 += h2v*owr[ct]; pv3 += h3v*owr[ct];
    }
    #pragma unroll
    for (int m = 1; m < 16; m <<= 1) {
        pv0 += __shfl_xor(pv0, m, 64);
        pv1 += __shfl_xor(pv1, m, 64);
        pv2 += __shfl_xor(pv2, m, 64);
        pv3 += __shfl_xor(pv3, m, 64);
    }
    if (col == 0) {
        size_t rbase = n0 + strip*16 + quad*4;
        val[rbase + 0] = pv0 + outb0;
        val[rbase + 1] = pv1 + outb0;
        val[rbase + 2] = pv2 + outb0;
        val[rbase + 3] = pv3 + outb0;
    }
}

// ---------------- launch ---------------------------------------------------
extern "C" void kernel_launch(void* const* d_in, const int* in_sizes, int n_in,
                              void* d_out, int out_size, void* d_ws, size_t ws_size,
                              hipStream_t stream) {
    const float* obs        = (const float*)d_in[0];
    const float* rnn        = (const float*)d_in[1];
    const float* enc_air_W  = (const float*)d_in[2];
    const float* enc_air_b  = (const float*)d_in[3];
    const float* enc_m_W    = (const float*)d_in[4];
    const float* enc_m_b    = (const float*)d_in[5];
    const float* air_Wih    = (const float*)d_in[6];
    const float* air_Whh    = (const float*)d_in[7];
    const float* air_bih    = (const float*)d_in[8];
    const float* air_bhh    = (const float*)d_in[9];
    const float* m_Wih      = (const float*)d_in[10];
    const float* m_Whh      = (const float*)d_in[11];
    const float* m_bih      = (const float*)d_in[12];
    const float* m_bhh      = (const float*)d_in[13];
    const float* attn_in_w  = (const float*)d_in[14];
    const float* attn_in_b  = (const float*)d_in[15];
    const float* attn_out_w = (const float*)d_in[16];
    const float* attn_out_b = (const float*)d_in[17];
    const float* mlp_W0     = (const float*)d_in[18];
    const float* mlp_b0     = (const float*)d_in[19];
    const float* mlp_W1     = (const float*)d_in[20];
    const float* mlp_b1     = (const float*)d_in[21];
    const float* out_W      = (const float*)d_in[22];
    const float* out_b      = (const float*)d_in[23];

    float* ws  = (float*)d_ws;
    float* out = (float*)d_out;

    prep_kernel<<<42, 256, 0, stream>>>(enc_air_W, enc_air_b, enc_m_W, enc_m_b,
                                        air_Wih, air_bih, m_Wih, m_bih,
                                        mlp_W0, mlp_W1, attn_in_w, attn_out_w, ws);

    gru_kernel<<<768, 256, 0, stream>>>(obs, rnn, ws,
                                        air_Whh, air_bhh, m_Whh, m_bhh,
                                        ws + OFF_AIRF, ws + OFF_MF, ws + OFF_MASK,
                                        out + NVAL);

    fused_kernel<<<NN/64, 256, 0, stream>>>(ws + OFF_AIRF, ws + OFF_MF, ws + OFF_MASK,
                                            (const unsigned short*)(ws + OFF_WQKV), attn_in_b,
                                            (const unsigned short*)(ws + OFF_WO),   attn_out_b,
                                            (const unsigned short*)(ws + OFF_W0P), mlp_b0,
                                            (const unsigned short*)(ws + OFF_W1P), mlp_b1,
                                            out_W, out_b, out);
}